// Round 1
// baseline (743.985 us; speedup 1.0000x reference)
//
#include <hip/hip_runtime.h>
#include <math.h>

#define B_  4
#define N_  4096
#define DIN 512
#define D_  64
#define QROWS 16
#define RPW 4

// ---------------------------------------------------------------------------
// Projection: K/Q/V[b,n,o] = sum_d x[b,n,d] * W[o,d]
// Tiled fp32 GEMM, BM=64 rows x BN=64 cols, BK=64, 256 threads, 4x4 micro-tile.
// blockIdx.y selects which W / output buffer.
// ---------------------------------------------------------------------------
__global__ __launch_bounds__(256) void proj_kernel(
    const float* __restrict__ X, const float* __restrict__ Wk,
    const float* __restrict__ Wq, const float* __restrict__ Wv,
    float* __restrict__ Kb, float* __restrict__ Qb, float* __restrict__ Vb)
{
    __shared__ float At[64 * 68];   // [d][row], pad 68 keeps float4 alignment + spreads banks
    __shared__ float Bt[64 * 68];   // [d][n]

    const int tid = threadIdx.x;
    const int rbase = blockIdx.x * 64;

    const float* W;
    float* Out;
    if (blockIdx.y == 0)      { W = Wk; Out = Kb; }
    else if (blockIdx.y == 1) { W = Wq; Out = Qb; }
    else                      { W = Wv; Out = Vb; }

    const int r0 = (tid & 15) * 4;
    const int n0 = (tid >> 4) * 4;

    float acc[4][4] = {};

    for (int kc = 0; kc < DIN; kc += 64) {
        // stage x-tile (transposed) and W-tile (transposed)
        #pragma unroll
        for (int i = 0; i < 4; ++i) {
            const int f   = tid + i * 256;      // 0..1023 float4s
            const int row = f >> 4;             // 0..63
            const int d4  = (f & 15) * 4;       // 0..60
            float4 xa = *(const float4*)(X + (size_t)(rbase + row) * DIN + kc + d4);
            At[(d4 + 0) * 68 + row] = xa.x;
            At[(d4 + 1) * 68 + row] = xa.y;
            At[(d4 + 2) * 68 + row] = xa.z;
            At[(d4 + 3) * 68 + row] = xa.w;
            float4 wb = *(const float4*)(W + (size_t)row * DIN + kc + d4);
            Bt[(d4 + 0) * 68 + row] = wb.x;
            Bt[(d4 + 1) * 68 + row] = wb.y;
            Bt[(d4 + 2) * 68 + row] = wb.z;
            Bt[(d4 + 3) * 68 + row] = wb.w;
        }
        __syncthreads();

        #pragma unroll 8
        for (int d = 0; d < 64; ++d) {
            float4 a4 = *(const float4*)&At[d * 68 + r0];
            float4 b4 = *(const float4*)&Bt[d * 68 + n0];
            float av[4] = {a4.x, a4.y, a4.z, a4.w};
            float bv[4] = {b4.x, b4.y, b4.z, b4.w};
            #pragma unroll
            for (int i = 0; i < 4; ++i)
                #pragma unroll
                for (int j = 0; j < 4; ++j)
                    acc[i][j] += av[i] * bv[j];
        }
        __syncthreads();
    }

    #pragma unroll
    for (int i = 0; i < 4; ++i) {
        *(float4*)&Out[(size_t)(rbase + r0 + i) * D_ + n0] =
            make_float4(acc[i][0], acc[i][1], acc[i][2], acc[i][3]);
    }
}

// ---------------------------------------------------------------------------
// Causal flash attention (fp32). Block = 16 query rows (4 waves x 4 rows each).
// K/V staged per 64-key chunk in LDS, pad 66 (conflict-free ds_read_b64 of K,
// conflict-free lane-consecutive V reads). Online softmax per row; p broadcast
// via v_readlane (VALU, keeps DS pipe free).
// ---------------------------------------------------------------------------
__device__ __forceinline__ float lane_bcast(float v, int l) {
    return __int_as_float(__builtin_amdgcn_readlane(__float_as_int(v), l));
}

__global__ __launch_bounds__(256) void attn_kernel(
    const float* __restrict__ Q, const float* __restrict__ K,
    const float* __restrict__ V, float* __restrict__ O)
{
    __shared__ float Ks[64 * 66];
    __shared__ float Vs[64 * 66];
    __shared__ float qs[QROWS * D_];

    const int tid  = threadIdx.x;
    const int lane = tid & 63;
    const int w    = tid >> 6;

    const int nqblk = N_ / QROWS;               // 256
    const int b     = blockIdx.x / nqblk;
    const int qbase = (blockIdx.x % nqblk) * QROWS;

    const float* Qblk = Q + ((size_t)b * N_ + qbase) * D_;
    #pragma unroll
    for (int i = 0; i < 4; ++i) {
        const int idx = tid + i * 256;          // 1024 floats = 16 rows x 64
        qs[idx] = Qblk[idx];
    }

    float m[RPW], l[RPW], acc[RPW], pk[RPW], scl[RPW];
    #pragma unroll
    for (int r = 0; r < RPW; ++r) { m[r] = -INFINITY; l[r] = 0.f; acc[r] = 0.f; }

    const int qi0 = w * RPW;
    const int nchunks = qbase / 64 + 1;         // qbase % 64 in {0,16,32,48}
    const float* Kbat = K + (size_t)b * N_ * D_;
    const float* Vbat = V + (size_t)b * N_ * D_;

    for (int c = 0; c < nchunks; ++c) {
        const int kbase = c * 64;
        __syncthreads();
        #pragma unroll
        for (int i = 0; i < 4; ++i) {
            const int f  = tid + i * 256;
            const int j  = f >> 4;
            const int d4 = (f & 15) * 4;
            const int base = j * 66 + d4;
            float4 kv = *(const float4*)(Kbat + (size_t)(kbase + j) * D_ + d4);
            *(float2*)&Ks[base]     = make_float2(kv.x, kv.y);
            *(float2*)&Ks[base + 2] = make_float2(kv.z, kv.w);
            float4 vv = *(const float4*)(Vbat + (size_t)(kbase + j) * D_ + d4);
            *(float2*)&Vs[base]     = make_float2(vv.x, vv.y);
            *(float2*)&Vs[base + 2] = make_float2(vv.z, vv.w);
        }
        __syncthreads();

        // phase A: lane = key j; scores for 4 rows
        float s[RPW] = {0.f, 0.f, 0.f, 0.f};
        const float* kp = &Ks[lane * 66];
        #pragma unroll 8
        for (int d = 0; d < D_; d += 2) {
            float2 kk = *(const float2*)(kp + d);
            #pragma unroll
            for (int r = 0; r < RPW; ++r) {
                float2 qq = *(const float2*)&qs[(qi0 + r) * D_ + d];
                s[r] += kk.x * qq.x + kk.y * qq.y;
            }
        }

        const int kj = kbase + lane;
        #pragma unroll
        for (int r = 0; r < RPW; ++r) {
            const int qr = qbase + qi0 + r;
            float sv = (kj <= qr) ? s[r] * 0.125f : -INFINITY;
            float mc = sv;
            #pragma unroll
            for (int off = 32; off > 0; off >>= 1)
                mc = fmaxf(mc, __shfl_xor(mc, off, 64));
            const float mn = fmaxf(m[r], mc);
            const float p  = __expf(sv - mn);        // masked lanes: exp(-inf)=0
            const float so = __expf(m[r] - mn);      // first chunk: exp(-inf)=0
            float ps = p;
            #pragma unroll
            for (int off = 32; off > 0; off >>= 1)
                ps += __shfl_xor(ps, off, 64);
            l[r] = l[r] * so + ps;
            m[r] = mn;
            scl[r] = so;
            pk[r]  = p;
        }

        // phase B: lane = output dim o
        #pragma unroll
        for (int r = 0; r < RPW; ++r) acc[r] *= scl[r];
        #pragma unroll 4
        for (int j = 0; j < 64; ++j) {
            const float vv = Vs[j * 66 + lane];
            #pragma unroll
            for (int r = 0; r < RPW; ++r)
                acc[r] += lane_bcast(pk[r], j) * vv;
        }
    }

    #pragma unroll
    for (int r = 0; r < RPW; ++r)
        O[((size_t)b * N_ + qbase + qi0 + r) * D_ + lane] = acc[r] / l[r];
}

// ---------------------------------------------------------------------------
extern "C" void kernel_launch(void* const* d_in, const int* in_sizes, int n_in,
                              void* d_out, int out_size, void* d_ws, size_t ws_size,
                              hipStream_t stream)
{
    const float* x  = (const float*)d_in[0];
    const float* Wk = (const float*)d_in[1];
    const float* Wq = (const float*)d_in[2];
    const float* Wv = (const float*)d_in[3];
    float* O = (float*)d_out;

    const size_t per = (size_t)B_ * N_ * D_;    // 1M floats each
    float* Kb = (float*)d_ws;
    float* Qb = Kb + per;
    float* Vb = Qb + per;

    dim3 pgrid(B_ * N_ / 64, 3);
    proj_kernel<<<pgrid, 256, 0, stream>>>(x, Wk, Wq, Wv, Kb, Qb, Vb);

    attn_kernel<<<dim3(B_ * (N_ / QROWS)), 256, 0, stream>>>(Qb, Kb, Vb, O);
}

// Round 2
// 95.990 us; speedup vs baseline: 7.7507x; 7.7507x over previous
//
#include <hip/hip_runtime.h>
#include <math.h>

#define N_   4096
#define DIN  512
#define D_   64

typedef __attribute__((ext_vector_type(8))) short  bf16x8;
typedef __attribute__((ext_vector_type(4))) float  f32x4;

__device__ __forceinline__ unsigned bf16rne(float x) {
    unsigned u = __float_as_uint(x);
    return (u + 0x7FFFu + ((u >> 16) & 1u)) >> 16;
}

// ---------------------------------------------------------------------------
// Projection: X[16384x512] fp32 -> bf16 MFMA GEMM vs Wk|Wq|Wv (192 outputs).
// Writes Kb, Qb n-major bf16 [16384][64]; V transposed: Vt [4][64][4096] bf16.
// Block: 256 thr / 4 waves, 64 n-rows, BK=64.
// ---------------------------------------------------------------------------
__global__ __launch_bounds__(256) void proj_kernel(
    const float* __restrict__ X, const float* __restrict__ Wk,
    const float* __restrict__ Wq, const float* __restrict__ Wv,
    unsigned short* __restrict__ Kb, unsigned short* __restrict__ Qb,
    unsigned short* __restrict__ Vt)
{
    __shared__ unsigned short Xs[64 * 72];    // [n][d] bf16, pad 72 (16B-aligned rows)
    __shared__ unsigned short Ws[192 * 72];   // [o][d] bf16: rows 0-63 Wk, 64-127 Wq, 128-191 Wv

    const int tid  = threadIdx.x;
    const int lane = tid & 63;
    const int w    = tid >> 6;
    const int q15  = lane & 15;
    const int hi   = lane >> 4;
    const int rbase = blockIdx.x * 64;

    f32x4 acc[12];
    #pragma unroll
    for (int i = 0; i < 12; ++i) acc[i] = (f32x4){0.f, 0.f, 0.f, 0.f};

    for (int kc = 0; kc < DIN; kc += 64) {
        __syncthreads();
        // stage X tile [64n][64d] -> bf16
        #pragma unroll
        for (int i = 0; i < 4; ++i) {
            const int idx = tid + i * 256;
            const int row = idx >> 4;
            const int d4  = (idx & 15) * 4;
            float4 xv = *(const float4*)(X + (size_t)(rbase + row) * DIN + kc + d4);
            unsigned p01 = bf16rne(xv.x) | (bf16rne(xv.y) << 16);
            unsigned p23 = bf16rne(xv.z) | (bf16rne(xv.w) << 16);
            *(uint2*)&Xs[row * 72 + d4] = make_uint2(p01, p23);
        }
        // stage W slice [192o][64d] -> bf16
        #pragma unroll
        for (int i = 0; i < 3; ++i) {
            const int idx  = tid + i * 256;          // 0..767
            const int wrow = idx >> 2;               // 0..191
            const int d16  = (idx & 3) * 16;
            const float* Wp = (wrow < 64)  ? Wk + (size_t)wrow * DIN
                            : (wrow < 128) ? Wq + (size_t)(wrow - 64) * DIN
                                           : Wv + (size_t)(wrow - 128) * DIN;
            #pragma unroll
            for (int jj = 0; jj < 4; ++jj) {
                float4 wv = *(const float4*)(Wp + kc + d16 + jj * 4);
                unsigned p01 = bf16rne(wv.x) | (bf16rne(wv.y) << 16);
                unsigned p23 = bf16rne(wv.z) | (bf16rne(wv.w) << 16);
                *(uint2*)&Ws[wrow * 72 + d16 + jj * 4] = make_uint2(p01, p23);
            }
        }
        __syncthreads();

        #pragma unroll
        for (int ks = 0; ks < 2; ++ks) {
            bf16x8 af = *(const bf16x8*)&Xs[(w * 16 + q15) * 72 + ks * 32 + hi * 8];
            #pragma unroll
            for (int ot = 0; ot < 12; ++ot) {
                bf16x8 bfr = *(const bf16x8*)&Ws[(ot * 16 + q15) * 72 + ks * 32 + hi * 8];
                acc[ot] = __builtin_amdgcn_mfma_f32_16x16x32_bf16(af, bfr, acc[ot], 0, 0, 0);
            }
        }
    }

    // epilogue: lane holds O[n = w*16 + hi*4 + r][o = ot*16 + q15]
    // K (ot 0-3) and Q (ot 4-7): direct bf16 stores, 16 lanes x 2B = 32B segments
    #pragma unroll
    for (int ot = 0; ot < 8; ++ot) {
        #pragma unroll
        for (int r = 0; r < 4; ++r) {
            const int n = w * 16 + hi * 4 + r;
            const int o = ot * 16 + q15;
            unsigned short v = (unsigned short)bf16rne(acc[ot][r]);
            if (ot < 4) Kb[(size_t)(rbase + n) * D_ + o]        = v;
            else        Qb[(size_t)(rbase + n) * D_ + (o - 64)] = v;
        }
    }
    // V: transpose via LDS (reuse Ws), then coalesced o-major store
    __syncthreads();
    unsigned short* Os = Ws;                      // [64n][66o]
    #pragma unroll
    for (int ot = 8; ot < 12; ++ot) {
        #pragma unroll
        for (int r = 0; r < 4; ++r) {
            const int n = w * 16 + hi * 4 + r;
            const int o = (ot - 8) * 16 + q15;
            Os[n * 66 + o] = (unsigned short)bf16rne(acc[ot][r]);
        }
    }
    __syncthreads();
    {
        const int o  = tid >> 2;                  // 0..63
        const int ng = (tid & 3) * 16;
        unsigned short tmp[16];
        #pragma unroll
        for (int i = 0; i < 16; ++i) tmp[i] = Os[(ng + i) * 66 + o];
        const int b  = rbase >> 12;
        const int nb = rbase & (N_ - 1);
        unsigned short* dst = Vt + ((size_t)b * D_ + o) * N_ + nb + ng;
        *(uint4*)dst       = *(uint4*)&tmp[0];
        *((uint4*)dst + 1) = *(uint4*)&tmp[8];
    }
}

// ---------------------------------------------------------------------------
// Flash attention, bf16 MFMA. Block = 2 waves x 16 q-rows; waves split KV
// chunks (64 keys) even/odd, LDS combine at end. Swapped QK^T: lane holds
// S^T[16 keys][q=lane&15]; softmax = 15 local max + shfl_xor(16,32).
// K / Vt fragments read directly from global (L2-resident).
// ---------------------------------------------------------------------------
__global__ __launch_bounds__(128) void attn_kernel(
    const unsigned short* __restrict__ Qb, const unsigned short* __restrict__ Kb,
    const unsigned short* __restrict__ Vt, float* __restrict__ O)
{
    __shared__ unsigned short Pbuf[2][16 * 72];   // per-wave P [q][key], pad 72
    __shared__ float Obuf[64 * 17];               // wave1 partial O^T [d][q]
    __shared__ float mlb[2][16];
    __shared__ float Ob2[16 * 68];                // merged O [q][d], pad 68

    const int tid  = threadIdx.x;
    const int lane = tid & 63;
    const int w    = tid >> 6;
    const int q15  = lane & 15;
    const int hi   = lane >> 4;

    // balanced bid -> (qi, b): CU set {j, j+256, j+512, j+768} sums to 510
    const int j  = blockIdx.x & 255;
    const int s  = blockIdx.x >> 8;
    const int qi = (s & 1) ? j : 255 - j;
    const int b  = s;
    const int qb = qi * 16;
    const int nch = (qi >> 2) + 1;

    const unsigned short* Qp = Qb + (size_t)b * N_ * D_;
    const unsigned short* Kp = Kb + (size_t)b * N_ * D_;
    const unsigned short* Vp = Vt + (size_t)b * D_ * N_;

    bf16x8 qf[2];
    #pragma unroll
    for (int ks = 0; ks < 2; ++ks)
        qf[ks] = *(const bf16x8*)(Qp + (size_t)(qb + q15) * D_ + ks * 32 + hi * 8);

    f32x4 accO[4];
    #pragma unroll
    for (int dt = 0; dt < 4; ++dt) accO[dt] = (f32x4){0.f, 0.f, 0.f, 0.f};
    float m = -INFINITY, lsum = 0.f;

    unsigned short* Pw = &Pbuf[w][0];
    const int qg = qb + q15;

    for (int c = w; c < nch; c += 2) {
        const int kbase = c * 64;
        const bool last = (c == nch - 1);

        // QK^T (swapped): A = K tile rows, B = Q^T
        bf16x8 kf[4][2];
        #pragma unroll
        for (int kt = 0; kt < 4; ++kt)
            #pragma unroll
            for (int ks = 0; ks < 2; ++ks)
                kf[kt][ks] = *(const bf16x8*)(Kp + (size_t)(kbase + kt * 16 + q15) * D_ + ks * 32 + hi * 8);

        f32x4 sv[4];
        #pragma unroll
        for (int kt = 0; kt < 4; ++kt) {
            sv[kt] = (f32x4){0.f, 0.f, 0.f, 0.f};
            #pragma unroll
            for (int ks = 0; ks < 2; ++ks)
                sv[kt] = __builtin_amdgcn_mfma_f32_16x16x32_bf16(kf[kt][ks], qf[ks], sv[kt], 0, 0, 0);
        }

        // scale + causal mask (only the last chunk straddles the diagonal)
        float x[4][4];
        float mloc = -INFINITY;
        #pragma unroll
        for (int kt = 0; kt < 4; ++kt)
            #pragma unroll
            for (int r = 0; r < 4; ++r) {
                float v = sv[kt][r] * 0.125f;
                if (last) {
                    const int kg = kbase + kt * 16 + hi * 4 + r;
                    v = (kg <= qg) ? v : -INFINITY;
                }
                x[kt][r] = v;
                mloc = fmaxf(mloc, v);
            }
        mloc = fmaxf(mloc, __shfl_xor(mloc, 16));
        mloc = fmaxf(mloc, __shfl_xor(mloc, 32));

        const float mn = fmaxf(m, mloc);
        const float sc = __expf(m - mn);
        float p[4][4], ps = 0.f;
        #pragma unroll
        for (int kt = 0; kt < 4; ++kt)
            #pragma unroll
            for (int r = 0; r < 4; ++r) {
                p[kt][r] = __expf(x[kt][r] - mn);
                ps += p[kt][r];
            }
        ps += __shfl_xor(ps, 16);
        ps += __shfl_xor(ps, 32);
        lsum = lsum * sc + ps;
        m = mn;
        #pragma unroll
        for (int dt = 0; dt < 4; ++dt) accO[dt] *= sc;

        // P -> LDS [q][key] bf16 (within-wave re-layout for the B-fragment)
        #pragma unroll
        for (int kt = 0; kt < 4; ++kt)
            #pragma unroll
            for (int rp = 0; rp < 2; ++rp) {
                unsigned pk = bf16rne(p[kt][2 * rp]) | (bf16rne(p[kt][2 * rp + 1]) << 16);
                *(unsigned*)&Pw[q15 * 72 + kt * 16 + hi * 4 + rp * 2] = pk;
            }

        // PV: O^T += V^T * P^T
        #pragma unroll
        for (int ks2 = 0; ks2 < 2; ++ks2) {
            bf16x8 pf = *(const bf16x8*)&Pw[q15 * 72 + ks2 * 32 + hi * 8];
            #pragma unroll
            for (int dt = 0; dt < 4; ++dt) {
                bf16x8 vf = *(const bf16x8*)(Vp + (size_t)(dt * 16 + q15) * N_ + kbase + ks2 * 32 + hi * 8);
                accO[dt] = __builtin_amdgcn_mfma_f32_16x16x32_bf16(vf, pf, accO[dt], 0, 0, 0);
            }
        }
    }

    // cross-wave flash combine
    if (w == 1) {
        #pragma unroll
        for (int dt = 0; dt < 4; ++dt)
            #pragma unroll
            for (int r = 0; r < 4; ++r)
                Obuf[(dt * 16 + hi * 4 + r) * 17 + q15] = accO[dt][r];
        if (hi == 0) { mlb[0][q15] = m; mlb[1][q15] = lsum; }
    }
    __syncthreads();
    if (w == 0) {
        const float m1 = mlb[0][q15], l1 = mlb[1][q15];
        const float M  = fmaxf(m, m1);
        const float a0 = __expf(m - M), a1 = __expf(m1 - M);
        const float L  = lsum * a0 + l1 * a1;
        const float rL = 1.0f / L;
        #pragma unroll
        for (int dt = 0; dt < 4; ++dt)
            #pragma unroll
            for (int r = 0; r < 4; ++r) {
                const float o1 = Obuf[(dt * 16 + hi * 4 + r) * 17 + q15];
                Ob2[q15 * 68 + dt * 16 + hi * 4 + r] = (accO[dt][r] * a0 + o1 * a1) * rL;
            }
    }
    __syncthreads();
    {
        const int row = tid >> 3;
        const int c8  = (tid & 7) * 8;
        float4 v0 = *(float4*)&Ob2[row * 68 + c8];
        float4 v1 = *(float4*)&Ob2[row * 68 + c8 + 4];
        float* dst = O + ((size_t)b * N_ + qb + row) * D_ + c8;
        *(float4*)dst       = v0;
        *(float4*)(dst + 4) = v1;
    }
}

// ---------------------------------------------------------------------------
extern "C" void kernel_launch(void* const* d_in, const int* in_sizes, int n_in,
                              void* d_out, int out_size, void* d_ws, size_t ws_size,
                              hipStream_t stream)
{
    const float* x  = (const float*)d_in[0];
    const float* Wk = (const float*)d_in[1];
    const float* Wq = (const float*)d_in[2];
    const float* Wv = (const float*)d_in[3];
    float* O = (float*)d_out;

    const size_t per = (size_t)4 * N_ * D_;       // 1M bf16 elements each
    unsigned short* Kb = (unsigned short*)d_ws;
    unsigned short* Qb = Kb + per;
    unsigned short* Vt = Qb + per;

    proj_kernel<<<dim3(4 * N_ / 64), 256, 0, stream>>>(x, Wk, Wq, Wv, Kb, Qb, Vt);
    attn_kernel<<<dim3(1024), 128, 0, stream>>>(Qb, Kb, Vt, O);
}

// Round 3
// 92.158 us; speedup vs baseline: 8.0729x; 1.0416x over previous
//
#include <hip/hip_runtime.h>
#include <hip/hip_bf16.h>
#include <math.h>

#define N_   4096
#define DIN  512
#define D_   64

typedef __attribute__((ext_vector_type(8))) short  bf16x8;
typedef __attribute__((ext_vector_type(4))) float  f32x4;

__device__ __forceinline__ unsigned short bf16rne(float x) {
    unsigned u = __float_as_uint(x);
    return (unsigned short)((u + 0x7FFFu + ((u >> 16) & 1u)) >> 16);
}
__device__ __forceinline__ unsigned cvt2(float a, float b) {
    __hip_bfloat162 h = __float22bfloat162_rn(make_float2(a, b));
    unsigned u; __builtin_memcpy(&u, &h, 4);
    return u;
}
__device__ __forceinline__ uint2 cvt4(float4 v) {
    return make_uint2(cvt2(v.x, v.y), cvt2(v.z, v.w));
}

// ---------------------------------------------------------------------------
// Projection GEMM: X[16384x512] fp32 -> {K,Q n-major bf16 [16384][64], Vt
// o-major bf16 [4][64][4096]}. 512 thr / 8 waves, BM=64, BK=64, LDS
// double-buffered (loads for kc+1 issue right after the barrier and overlap
// MFMA + cvt of kc). Wave (rt,oh): rows rt*16..+16, output cols oh*96..+96.
// ---------------------------------------------------------------------------
__global__ __launch_bounds__(512) void proj_kernel(
    const float* __restrict__ X, const float* __restrict__ Wk,
    const float* __restrict__ Wq, const float* __restrict__ Wv,
    unsigned short* __restrict__ Kb, unsigned short* __restrict__ Qb,
    unsigned short* __restrict__ Vt)
{
    __shared__ unsigned short Xs[2][64 * 72];
    __shared__ unsigned short Ws[2][192 * 72];

    const int tid  = threadIdx.x;
    const int lane = tid & 63;
    const int w    = tid >> 6;
    const int q15  = lane & 15;
    const int hi   = lane >> 4;
    const int rt   = w >> 1;
    const int oh   = w & 1;
    const int rbase = blockIdx.x * 64;

    float4 xr[2], wr[6];

    auto loadT = [&](int kc) {
        #pragma unroll
        for (int i = 0; i < 2; ++i) {
            const int idx = tid + i * 512;
            xr[i] = *(const float4*)(X + (size_t)(rbase + (idx >> 4)) * DIN + kc + (idx & 15) * 4);
        }
        #pragma unroll
        for (int i = 0; i < 6; ++i) {
            const int idx  = tid + i * 512;
            const int wrow = idx >> 4;
            const float* Wp = (wrow < 64)  ? Wk + (size_t)wrow * DIN
                            : (wrow < 128) ? Wq + (size_t)(wrow - 64) * DIN
                                           : Wv + (size_t)(wrow - 128) * DIN;
            wr[i] = *(const float4*)(Wp + kc + (idx & 15) * 4);
        }
    };
    auto storeT = [&](int p) {
        #pragma unroll
        for (int i = 0; i < 2; ++i) {
            const int idx = tid + i * 512;
            *(uint2*)&Xs[p][(idx >> 4) * 72 + (idx & 15) * 4] = cvt4(xr[i]);
        }
        #pragma unroll
        for (int i = 0; i < 6; ++i) {
            const int idx = tid + i * 512;
            *(uint2*)&Ws[p][(idx >> 4) * 72 + (idx & 15) * 4] = cvt4(wr[i]);
        }
    };

    f32x4 acc[6];
    #pragma unroll
    for (int i = 0; i < 6; ++i) acc[i] = (f32x4){0.f, 0.f, 0.f, 0.f};

    loadT(0);
    int p = 0;
    for (int it = 0; it < 8; ++it) {
        storeT(p);
        __syncthreads();
        if (it < 7) loadT((it + 1) * 64);
        #pragma unroll
        for (int ks = 0; ks < 2; ++ks) {
            bf16x8 af = *(const bf16x8*)&Xs[p][(rt * 16 + q15) * 72 + ks * 32 + hi * 8];
            #pragma unroll
            for (int j = 0; j < 6; ++j) {
                bf16x8 bfr = *(const bf16x8*)&Ws[p][((oh * 6 + j) * 16 + q15) * 72 + ks * 32 + hi * 8];
                acc[j] = __builtin_amdgcn_mfma_f32_16x16x32_bf16(af, bfr, acc[j], 0, 0, 0);
            }
        }
        p ^= 1;
    }

    // epilogue: lane holds O[n = rt*16 + hi*4 + r][o = (oh*6+j)*16 + q15]
    unsigned short* Os = &Ws[0][0];               // [64n][66o] V staging
    #pragma unroll
    for (int j = 0; j < 6; ++j) {
        const int og = oh * 6 + j;
        #pragma unroll
        for (int r = 0; r < 4; ++r) {
            const int n = rt * 16 + hi * 4 + r;
            const int o = og * 16 + q15;
            unsigned short v = bf16rne(acc[j][r]);
            if (og < 4)      Kb[(size_t)(rbase + n) * D_ + o]        = v;
            else if (og < 8) Qb[(size_t)(rbase + n) * D_ + (o - 64)] = v;
            else             Os[n * 66 + (o - 128)]                  = v;
        }
    }
    __syncthreads();
    {
        const int o  = tid >> 3;                  // 0..63
        const int ng = (tid & 7) * 8;             // 0..56
        unsigned short tmp[8];
        #pragma unroll
        for (int i = 0; i < 8; ++i) tmp[i] = Os[(ng + i) * 66 + o];
        const int b  = rbase >> 12;
        const int nb = rbase & (N_ - 1);
        *(uint4*)(Vt + ((size_t)b * D_ + o) * N_ + nb + ng) = *(uint4*)&tmp[0];
    }
}

// ---------------------------------------------------------------------------
// Flash attention, bf16 MFMA. Block = 4 waves, one 16-row q-tile, k-split:
// wave w handles chunks {w, w+4, ...} of 64 keys; 4-way LDS flash combine.
// Swapped QK^T (lane-local softmax cols); V-frags prefetched before softmax;
// exp in base-2 domain; P packed with v_cvt_pk_bf16_f32.
// ---------------------------------------------------------------------------
__global__ __launch_bounds__(256, 4) void attn_kernel(
    const unsigned short* __restrict__ Qb, const unsigned short* __restrict__ Kb,
    const unsigned short* __restrict__ Vt, float* __restrict__ O)
{
    __shared__ unsigned short Pbuf[4][16 * 72];
    __shared__ float Obuf[3][64 * 17];
    __shared__ float mlb[4][2][16];
    __shared__ float Ob2[16 * 68];

    const int tid  = threadIdx.x;
    const int lane = tid & 63;
    const int w    = tid >> 6;
    const int q15  = lane & 15;
    const int hi   = lane >> 4;

    // per-CU-balanced map: consecutive bids pair qi=u with qi=255-u
    const int u  = blockIdx.x >> 2;
    const int s  = blockIdx.x & 3;
    const int b  = s;
    const int qi = (s & 1) ? u : 255 - u;
    const int qb = qi * 16;
    const int nch = (qb >> 6) + 1;

    const unsigned short* Qp = Qb + (size_t)b * N_ * D_;
    const unsigned short* Kp = Kb + (size_t)b * N_ * D_;
    const unsigned short* Vp = Vt + (size_t)b * D_ * N_;

    bf16x8 qf[2];
    #pragma unroll
    for (int ks = 0; ks < 2; ++ks)
        qf[ks] = *(const bf16x8*)(Qp + (size_t)(qb + q15) * D_ + ks * 32 + hi * 8);

    f32x4 accO[4];
    #pragma unroll
    for (int dt = 0; dt < 4; ++dt) accO[dt] = (f32x4){0.f, 0.f, 0.f, 0.f};
    float m = -INFINITY, lsum = 0.f;

    unsigned short* Pw = &Pbuf[w][0];
    const int qg = qb + q15;
    const float SC = 0.125f * 1.44269504f;        // scale into log2 domain

    for (int c = w; c < nch; c += 4) {
        const int kbase = c * 64;
        const bool last = (c == nch - 1);

        // QK^T (swapped): A = K rows, B = Q^T
        bf16x8 kf[4][2];
        #pragma unroll
        for (int kt = 0; kt < 4; ++kt)
            #pragma unroll
            for (int ks = 0; ks < 2; ++ks)
                kf[kt][ks] = *(const bf16x8*)(Kp + (size_t)(kbase + kt * 16 + q15) * D_ + ks * 32 + hi * 8);

        f32x4 sv[4];
        #pragma unroll
        for (int kt = 0; kt < 4; ++kt) {
            sv[kt] = (f32x4){0.f, 0.f, 0.f, 0.f};
            #pragma unroll
            for (int ks = 0; ks < 2; ++ks)
                sv[kt] = __builtin_amdgcn_mfma_f32_16x16x32_bf16(kf[kt][ks], qf[ks], sv[kt], 0, 0, 0);
        }

        // prefetch V fragments; latency hides under softmax
        bf16x8 vf[2][4];
        #pragma unroll
        for (int ks2 = 0; ks2 < 2; ++ks2)
            #pragma unroll
            for (int dt = 0; dt < 4; ++dt)
                vf[ks2][dt] = *(const bf16x8*)(Vp + (size_t)(dt * 16 + q15) * N_ + kbase + ks2 * 32 + hi * 8);

        // softmax (log2 domain)
        float x[4][4];
        float mloc = -INFINITY;
        #pragma unroll
        for (int kt = 0; kt < 4; ++kt)
            #pragma unroll
            for (int r = 0; r < 4; ++r) {
                float v = sv[kt][r] * SC;
                if (last) {
                    const int kg = kbase + kt * 16 + hi * 4 + r;
                    v = (kg <= qg) ? v : -INFINITY;
                }
                x[kt][r] = v;
                mloc = fmaxf(mloc, v);
            }
        mloc = fmaxf(mloc, __shfl_xor(mloc, 16));
        mloc = fmaxf(mloc, __shfl_xor(mloc, 32));

        const float mn = fmaxf(m, mloc);
        const float sc = __builtin_amdgcn_exp2f(m - mn);
        float ps = 0.f;
        #pragma unroll
        for (int kt = 0; kt < 4; ++kt)
            #pragma unroll
            for (int r = 0; r < 4; ++r) {
                x[kt][r] = __builtin_amdgcn_exp2f(x[kt][r] - mn);
                ps += x[kt][r];
            }
        ps += __shfl_xor(ps, 16);
        ps += __shfl_xor(ps, 32);
        lsum = lsum * sc + ps;
        m = mn;
        #pragma unroll
        for (int dt = 0; dt < 4; ++dt) accO[dt] *= sc;

        // P -> per-wave LDS [q][key] bf16 (merged b64 writes)
        #pragma unroll
        for (int kt = 0; kt < 4; ++kt)
            *(uint2*)&Pw[q15 * 72 + kt * 16 + hi * 4] =
                make_uint2(cvt2(x[kt][0], x[kt][1]), cvt2(x[kt][2], x[kt][3]));

        // PV: O^T += V^T * P^T
        #pragma unroll
        for (int ks2 = 0; ks2 < 2; ++ks2) {
            bf16x8 pf = *(const bf16x8*)&Pw[q15 * 72 + ks2 * 32 + hi * 8];
            #pragma unroll
            for (int dt = 0; dt < 4; ++dt)
                accO[dt] = __builtin_amdgcn_mfma_f32_16x16x32_bf16(vf[ks2][dt], pf, accO[dt], 0, 0, 0);
        }
    }

    // 4-way flash combine
    if (w > 0) {
        #pragma unroll
        for (int dt = 0; dt < 4; ++dt)
            #pragma unroll
            for (int r = 0; r < 4; ++r)
                Obuf[w - 1][(dt * 16 + hi * 4 + r) * 17 + q15] = accO[dt][r];
    }
    if (hi == 0) { mlb[w][0][q15] = m; mlb[w][1][q15] = lsum; }
    __syncthreads();
    if (w == 0) {
        float mw[3], lw[3];
        #pragma unroll
        for (int j = 0; j < 3; ++j) { mw[j] = mlb[j + 1][0][q15]; lw[j] = mlb[j + 1][1][q15]; }
        const float M = fmaxf(fmaxf(m, mw[0]), fmaxf(mw[1], mw[2]));
        const float a0 = __builtin_amdgcn_exp2f(m - M);
        float L = lsum * a0;
        float aj[3];
        #pragma unroll
        for (int j = 0; j < 3; ++j) { aj[j] = __builtin_amdgcn_exp2f(mw[j] - M); L += lw[j] * aj[j]; }
        const float rL = 1.0f / L;
        #pragma unroll
        for (int dt = 0; dt < 4; ++dt)
            #pragma unroll
            for (int r = 0; r < 4; ++r) {
                const int d = dt * 16 + hi * 4 + r;
                float o = accO[dt][r] * a0;
                #pragma unroll
                for (int j = 0; j < 3; ++j) o += Obuf[j][d * 17 + q15] * aj[j];
                Ob2[q15 * 68 + d] = o * rL;
            }
    }
    __syncthreads();
    {
        const int row = tid >> 4;                 // 0..15
        const int c4  = (tid & 15) * 4;           // 0..60
        float4 v = *(float4*)&Ob2[row * 68 + c4];
        *(float4*)(O + ((size_t)b * N_ + qb + row) * D_ + c4) = v;
    }
}

// ---------------------------------------------------------------------------
extern "C" void kernel_launch(void* const* d_in, const int* in_sizes, int n_in,
                              void* d_out, int out_size, void* d_ws, size_t ws_size,
                              hipStream_t stream)
{
    const float* x  = (const float*)d_in[0];
    const float* Wk = (const float*)d_in[1];
    const float* Wq = (const float*)d_in[2];
    const float* Wv = (const float*)d_in[3];
    float* O = (float*)d_out;

    const size_t per = (size_t)4 * N_ * D_;       // 1M bf16 elements each
    unsigned short* Kb = (unsigned short*)d_ws;
    unsigned short* Qb = Kb + per;
    unsigned short* Vt = Qb + per;

    proj_kernel<<<dim3(4 * N_ / 64), 512, 0, stream>>>(x, Wk, Wq, Wv, Kb, Qb, Vt);
    attn_kernel<<<dim3(1024), 256, 0, stream>>>(Qb, Kb, Vt, O);
}